// Round 8
// baseline (154.648 us; speedup 1.0000x reference)
//
#include <hip/hip_runtime.h>
#include <math.h>

// Problem constants
#define BB   8
#define SS   100
#define TT   1200        // S * DMAX
#define NM   80          // NMEL
#define DMC  128         // DM
#define KK   9
#define G3   384         // 3*DM
#define NROW (BB*TT)     // 9600

typedef __attribute__((ext_vector_type(8))) short short8;
typedef __attribute__((ext_vector_type(4))) float f32x4;
typedef __attribute__((ext_vector_type(2))) float f32x2;

__device__ __forceinline__ float sigmoid_(float v) { return 1.f / (1.f + __expf(-v)); }
__device__ __forceinline__ float tanh_(float v) {
    float a = fabsf(v);
    float e = __expf(-2.f * a);
    float t = (1.f - e) / (1.f + e);
    return copysignf(t, v);
}
__device__ __forceinline__ unsigned short f2bf(float f) {   // RNE fp32->bf16
    unsigned int u = __float_as_uint(f);
    unsigned int r = (u + 0x7fffu + ((u >> 16) & 1u)) >> 16;
    return (unsigned short)r;
}
// CDNA packed fp32 ops (VOP3P)
__device__ __forceinline__ f32x2 pk_fma(f32x2 a, f32x2 b, f32x2 c) {
    f32x2 d;
    asm("v_pk_fma_f32 %0, %1, %2, %3" : "=v"(d) : "v"(a), "v"(b), "v"(c));
    return d;
}
__device__ __forceinline__ f32x2 pk_add(f32x2 a, f32x2 b) {
    f32x2 d;
    asm("v_pk_add_f32 %0, %1, %2" : "=v"(d) : "v"(a), "v"(b));
    return d;
}
// butterfly reduce steps: xor1/xor2 via DPP quad_perm (VALU pipe, no LDS),
// xor4 via ds_swizzle. Same pairwise sums as __shfl_xor -> bit-identical.
__device__ __forceinline__ f32x2 red_x1(f32x2 c) {
    f32x2 o;
    o[0] = __int_as_float(__builtin_amdgcn_mov_dpp(__float_as_int(c[0]), 0xB1, 0xF, 0xF, true));
    o[1] = __int_as_float(__builtin_amdgcn_mov_dpp(__float_as_int(c[1]), 0xB1, 0xF, 0xF, true));
    return pk_add(c, o);
}
__device__ __forceinline__ f32x2 red_x2(f32x2 c) {
    f32x2 o;
    o[0] = __int_as_float(__builtin_amdgcn_mov_dpp(__float_as_int(c[0]), 0x4E, 0xF, 0xF, true));
    o[1] = __int_as_float(__builtin_amdgcn_mov_dpp(__float_as_int(c[1]), 0x4E, 0xF, 0xF, true));
    return pk_add(c, o);
}
__device__ __forceinline__ f32x2 red_x4(f32x2 c) {
    f32x2 o;
    o[0] = __int_as_float(__builtin_amdgcn_ds_swizzle(__float_as_int(c[0]), 0x101F));
    o[1] = __int_as_float(__builtin_amdgcn_ds_swizzle(__float_as_int(c[1]), 0x101F));
    return pk_add(c, o);
}

// ---------------------------------------------------------------------------
// Kernel CP (R19): R16 block shape (256 thr, 2 barriers) but each THREAD
// carries TWO row-pairs (A = rows t0,t0+1 ; B = rows t0+2,t0+3) in the same
// instruction stream: weight loads/packing/slides/reduce amortized 2x, yv
// chain ILP doubled (8 indep chains), blocks halved to 2400 with unchanged
// barrier topology. Per-pair math order identical to R16 -> bit-identical.
// __launch_bounds__(256,2): VGPR cap 256 so the doubled accumulators fit.
//   prep path (bx>=300): tables + scan (256-thread indexing, as R16).
// ---------------------------------------------------------------------------
__global__ __launch_bounds__(256, 2) void k_convprep(
    const float* __restrict__ mel, const int* __restrict__ mel_len,
    const float* __restrict__ w1, const float* __restrict__ g1, const float* __restrict__ be1,
    const float* __restrict__ w2, const float* __restrict__ g2, const float* __restrict__ be2,
    float* __restrict__ xout,
    const float* __restrict__ whf, const float* __restrict__ whb,
    const float* __restrict__ wif, const float* __restrict__ wib,
    const float* __restrict__ bf, const float* __restrict__ bbv,
    const int* __restrict__ dur,
    unsigned short* __restrict__ wph, unsigned short* __restrict__ wpl,
    unsigned short* __restrict__ wih_h, unsigned short* __restrict__ wih_l,
    float* __restrict__ biasc, int* __restrict__ starts) {
    int bx = blockIdx.x;
    int b  = blockIdx.y;
    int tid = threadIdx.x;

    if (bx >= 300) {
        // ---------------- prep path (88 pids x 256 threads) ----------------
        int pid = (bx - 300) * 8 + b;            // [0, 88)
        if (pid < 87) {
            int u = pid * 256 + tid;             // [0, 22272)
            if (u < 12288) {
                int idx = u;                     // whh split-bf16
                int lane = idx & 63;
                int k32  = (idx >> 6) & 3;
                int tau  = (idx >> 8) % 24;
                int dirp = idx / (24 * 4 * 64);
                const float* w = dirp ? whb : whf;
                int gg = tau * 16 + (lane & 15);
                int kbase = k32 * 32 + (lane >> 4) * 8;
#pragma unroll
                for (int j = 0; j < 8; j++) {
                    float v = w[gg * DMC + kbase + j];
                    unsigned short hi = f2bf(v);
                    float hif = __uint_as_float(((unsigned)hi) << 16);
                    unsigned short lo = f2bf(v - hif);
                    wph[idx * 8 + j] = hi;
                    wpl[idx * 8 + j] = lo;
                }
            } else if (u < 21504) {
                int idx = u - 12288;             // wih split-bf16, [0, 9216)
                int lane = idx & 63;
                int ks   = (idx >> 6) % 3;
                int tau  = idx / (3 * 64);       // 0..47 ; dir = tau>=24
                int gate = tau * 16 + (lane & 15);
                int kb   = ks * 32 + (lane >> 4) * 8;
                const float* w = (gate < G3) ? (wif + gate * NM) : (wib + (gate - G3) * NM);
#pragma unroll
                for (int j = 0; j < 8; j++) {
                    int k = kb + j;
                    float v = (k < NM) ? w[k] : 0.f;
                    unsigned short hi = f2bf(v);
                    float hif = __uint_as_float(((unsigned)hi) << 16);
                    unsigned short lo = f2bf(v - hif);
                    wih_h[idx * 8 + j] = hi;
                    wih_l[idx * 8 + j] = lo;
                }
            } else {
                int v = u - 21504;               // biasc, [0, 768)
                biasc[v] = (v < G3) ? bf[v] : bbv[v - G3];
            }
        } else {
            // exclusive-scan of durations: 8 batches x 100, 32 lanes/batch
            int batch = tid >> 5, l = tid & 31;
            int run = 0;
#pragma unroll
            for (int c = 0; c < 4; c++) {
                int s = c * 32 + l;
                int v = (s < SS) ? dur[batch * SS + s] : 0;
                int xv = v;
#pragma unroll
                for (int off = 1; off < 32; off <<= 1) {
                    int t = __shfl_up(xv, off, 32);
                    if (l >= off) xv += t;
                }
                if (s < SS) starts[batch * SS + s] = run + xv - v;
                run += __shfl(xv, 31, 32);
            }
        }
        return;
    }

    // ------------------- conv path: 2 row-pairs per thread -------------------
    int ml = mel_len[b];
    int t0 = bx * 4;                             // rows t0 .. t0+3
    if (t0 >= ml) return;
    bool liveB = (t0 + 2 < ml);

    __shared__ __align__(16) f32x2 mp2[2][96];        // [pair][win]
    __shared__ __align__(16) f32x2 part2[2][8][82];   // [pair][octet][col]

    int mq = tid >> 6, g = tid & 63;
    int ms = 20 * mq;
    const float inv_sqrt = 0.9999950000374997f;  // 1/sqrt(1+1e-5)

    if (tid < 192) {
        int rr = tid / 96, i = tid - rr * 96;
        float vA = 0.f, vB = 0.f;
        if (i >= 8 && i < 88) {
            vA = mel[(b * TT + t0 + rr) * NM + i - 8];
            if (liveB) vB = mel[(b * TT + t0 + 2 + rr) * NM + i - 8];
        }
        ((float*)mp2[0])[i * 2 + rr] = vA;
        ((float*)mp2[1])[i * 2 + rr] = vB;
    }

    // ---- hoisted raw weight loads + BN2 scalars (latency hidden by barrier) ----
    float w1r[2][KK], w2r[2][KK], g1r[2], be1r[2];
#pragma unroll
    for (int dd = 0; dd < 2; dd++) {
        int d = g + 64 * dd;
#pragma unroll
        for (int k = 0; k < KK; k++) {
            w1r[dd][k] = w1[d * KK + k];
            w2r[dd][k] = w2[d * KK + k];
        }
        g1r[dd]  = g1[d];
        be1r[dd] = be1[d];
    }
    float g2s  = g2[0] * inv_sqrt;
    float be2s = be2[0];

    __syncthreads();

    f32x2 cA[20], cB[20];
#pragma unroll
    for (int m = 0; m < 20; m++) { cA[m] = (f32x2){0.f, 0.f}; cB[m] = (f32x2){0.f, 0.f}; }

#pragma unroll
    for (int dd = 0; dd < 2; dd++) {
        float sc = g1r[dd] * inv_sqrt;
        f32x2 w1p[KK], w2p[KK];
#pragma unroll
        for (int k = 0; k < KK; k++) {
            float a  = w1r[dd][k] * sc;
            float bq = w2r[dd][k];
            w1p[k] = (f32x2){a, a};
            w2p[k] = (f32x2){bq, bq};
        }
        float sb = be1r[dd];
        f32x2 sbp = (f32x2){sb, sb};

        f32x2 mwA[12], mwB[12];
        {
            const float4* p4A = (const float4*)(mp2[0] + ms);
            const float4* p4B = (const float4*)(mp2[1] + ms);
#pragma unroll
            for (int q = 0; q < 6; q++) {
                float4 vA = p4A[q], vB = p4B[q];
                mwA[2 * q]     = (f32x2){vA.x, vA.y};
                mwA[2 * q + 1] = (f32x2){vA.z, vA.w};
                mwB[2 * q]     = (f32x2){vB.x, vB.y};
                mwB[2 * q + 1] = (f32x2){vB.z, vB.w};
            }
        }
#pragma unroll
        for (int ch = 0; ch < 7; ch++) {
            // wave-uniform halo skip (bit-identical: skipped terms were
            // exact zeros in the leading accumulation slots).
            bool liveg = true;
            if (ch == 0) liveg = (mq != 0);
            if (ch == 6) liveg = (mq != 3);
            if (liveg) {
                f32x2 yvA4[4], yvB4[4];
#pragma unroll
                for (int jj = 0; jj < 4; jj++) {
                    f32x2 yvA = sbp, yvB = sbp;
#pragma unroll
                    for (int k = 0; k < KK; k++) {
                        yvA = pk_fma(w1p[k], mwA[jj + k], yvA);
                        yvB = pk_fma(w1p[k], mwB[jj + k], yvB);
                    }
                    yvA[0] = fmaxf(yvA[0], 0.f);
                    yvA[1] = fmaxf(yvA[1], 0.f);
                    yvB[0] = fmaxf(yvB[0], 0.f);
                    yvB[1] = fmaxf(yvB[1], 0.f);
                    yvA4[jj] = yvA;
                    yvB4[jj] = yvB;
                }
#pragma unroll
                for (int jj = 0; jj < 4; jj++) {
                    int off = ch * 4 + jj;
#pragma unroll
                    for (int k = 0; k < KK; k++) {
                        int mo = off - k;
                        if (mo >= 0 && mo < 20) {
                            cA[mo] = pk_fma(w2p[k], yvA4[jj], cA[mo]);
                            cB[mo] = pk_fma(w2p[k], yvB4[jj], cB[mo]);
                        }
                    }
                }
            }
            if (ch < 6) {   // slide both windows by 4
#pragma unroll
                for (int q = 0; q < 8; q++) { mwA[q] = mwA[q + 4]; mwB[q] = mwB[q + 4]; }
                const float4* p4A = (const float4*)(mp2[0] + ms + ch * 4 + 12);
                const float4* p4B = (const float4*)(mp2[1] + ms + ch * 4 + 12);
                float4 a0 = p4A[0], a1 = p4A[1];
                float4 b0 = p4B[0], b1 = p4B[1];
                mwA[8]  = (f32x2){a0.x, a0.y};
                mwA[9]  = (f32x2){a0.z, a0.w};
                mwA[10] = (f32x2){a1.x, a1.y};
                mwA[11] = (f32x2){a1.z, a1.w};
                mwB[8]  = (f32x2){b0.x, b0.y};
                mwB[9]  = (f32x2){b0.z, b0.w};
                mwB[10] = (f32x2){b1.x, b1.y};
                mwB[11] = (f32x2){b1.z, b1.w};
            }
        }
    }

    // ---- butterfly reduce over g within octets (DPP + swizzle), both pairs ----
#pragma unroll
    for (int m = 0; m < 20; m++) {
        cA[m] = red_x1(cA[m]);
        cB[m] = red_x1(cB[m]);
        cA[m] = red_x2(cA[m]);
        cB[m] = red_x2(cB[m]);
        cA[m] = red_x4(cA[m]);
        cB[m] = red_x4(cB[m]);
    }
    if ((g & 7) == 0) {
        int p = g >> 3;
#pragma unroll
        for (int m = 0; m < 20; m++) {
            part2[0][p][ms + m] = cA[m];
            part2[1][p][ms + m] = cB[m];
        }
    }
    __syncthreads();

    // ---- final: sum 8 octet partials + BN2/ReLU + store (4 rows) ----
    if (tid < 160) {
        int rr = (tid >= 80) ? 1 : 0;
        int m  = tid - 80 * rr;
#pragma unroll
        for (int pp = 0; pp < 2; pp++) {
            int t = t0 + pp * 2 + rr;
            if (t < ml) {
                float s = 0.f;
#pragma unroll
                for (int p = 0; p < 8; p++) s += part2[pp][p][m][rr];
                float v = fmaxf(0.f, fmaf(s, g2s, be2s));
                xout[(b * TT + t) * NM + m] = v;
            }
        }
    }
}

// ---------------------------------------------------------------------------
// Kernel C (unchanged): fused projection+GRU.
// ---------------------------------------------------------------------------
__global__ __launch_bounds__(512, 2) void k_gru(
    const float* __restrict__ x,
    const unsigned short* __restrict__ wph, const unsigned short* __restrict__ wpl,
    const unsigned short* __restrict__ wih_h, const unsigned short* __restrict__ wih_l,
    const float* __restrict__ biasc,
    const int* __restrict__ dur_all, const int* __restrict__ starts,
    const int* __restrict__ src_len,
    const float* __restrict__ bhf, const float* __restrict__ bhb,
    float* __restrict__ out) {
    int sblk = blockIdx.x;   // 0..6
    int b    = blockIdx.y;   // 0..7
    int dir  = blockIdx.z;   // 0 fwd, 1 bwd
    int s0 = sblk * 16;

    __shared__ __align__(16) short8 xbh[12][192];           // x B-frags hi, all iters
    __shared__ __align__(16) short8 xbl[12][192];           // x B-frags lo
    __shared__ __align__(16) unsigned short hbh[2][2048];   // h B-frags hi (pp)
    __shared__ __align__(16) unsigned short hbl[2][2048];   // h B-frags lo (pp)
    __shared__ int sdur[16], sstart[16];

    int tid  = threadIdx.x;
    int wave = tid >> 6, lane = tid & 63;
    int quad = lane >> 4, seg = lane & 15;

    if (tid < 16) {
        int ss = s0 + tid;
        sdur[tid]   = (ss < SS) ? dur_all[b * SS + ss] : 0;
        sstart[tid] = (ss < SS) ? starts[b * SS + ss]  : 0;
    }
    for (int i = tid; i < 2048; i += 512) { hbh[0][i] = 0; hbl[0][i] = 0; }

    // ---- w_hh A-frags (taus wave, wave+8, wave+16), persist in regs ----
    short8 Ah[3][4], Al[3][4];
    const short8* wph8 = (const short8*)wph;
    const short8* wpl8 = (const short8*)wpl;
#pragma unroll
    for (int tt = 0; tt < 3; tt++)
#pragma unroll
        for (int k32 = 0; k32 < 4; k32++) {
            int idx = ((dir * 24 + wave + 8 * tt) * 4 + k32) * 64 + lane;
            Ah[tt][k32] = wph8[idx];
            Al[tt][k32] = wpl8[idx];
        }
    // ---- w_ih A-frags (same taus, K=96), persist in regs ----
    short8 Gh[3][3], Gl[3][3];
    const short8* wih_h8 = (const short8*)wih_h;
    const short8* wih_l8 = (const short8*)wih_l;
#pragma unroll
    for (int tt = 0; tt < 3; tt++)
#pragma unroll
        for (int ks = 0; ks < 3; ks++) {
            int idx = ((dir * 24 + wave + 8 * tt) * 3 + ks) * 64 + lane;
            Gh[tt][ks] = wih_h8[idx];
            Gl[tt][ks] = wih_l8[idx];
        }

    // ---- per-lane meta & biases ----
    int s = s0 + seg;
    int sd = (s < SS) ? dur_all[b * SS + s] : 0;
    int slb = src_len[b];
    const float* bih = biasc + dir * G3;
    const float* bhh = dir ? bhb : bhf;
    int j0 = wave * 16 + quad * 4;
    float4 i_r = *(const float4*)&bih[j0];
    float4 i_z = *(const float4*)&bih[DMC + j0];
    float4 bxn = *(const float4*)&bih[2 * DMC + j0];
    float4 h_r = *(const float4*)&bhh[j0];
    float4 h_z = *(const float4*)&bhh[DMC + j0];
    float4 bhn = *(const float4*)&bhh[2 * DMC + j0];
    float4 br = make_float4(i_r.x + h_r.x, i_r.y + h_r.y, i_r.z + h_r.z, i_r.w + h_r.w);
    float4 bz = make_float4(i_z.x + h_z.x, i_z.y + h_z.y, i_z.z + h_z.z, i_z.w + h_z.w);
    float4 h = make_float4(0.f, 0.f, 0.f, 0.f);

    int idx8 = (j0 >> 5) * 64 + ((j0 >> 3) & 3) * 16 + seg;
    int wbase = idx8 * 8 + (j0 & 7);             // h-frag write addr (shorts)

    __syncthreads();   // sdur/sstart + h[0] frags visible

    // ---- stage ALL x B-frags (12 iters x 192 frag-lanes = 2304 tasks) ----
#pragma unroll
    for (int q = 0; q < 5; q++) {
        int u = tid + q * 512;
        if (u < 12 * 192) {
            int it  = u / 192;
            int rem = u - it * 192;
            int ks = rem >> 6, ln = rem & 63;
            int sg = ln & 15, qq = ln >> 4;
            int kb = ks * 32 + qq * 8;
            short8 hi8 = {0,0,0,0,0,0,0,0}, lo8 = {0,0,0,0,0,0,0,0};
            int d2 = sdur[sg];
            if (kb < NM && it < d2) {
                int t = dir ? (sstart[sg] + d2 - 1 - it) : (sstart[sg] + it);
                const float* xr = x + (size_t)(b * TT + t) * NM + kb;
#pragma unroll
                for (int j = 0; j < 8; j++) {
                    float v = xr[j];
                    unsigned short hi = f2bf(v);
                    hi8[j] = (short)hi;
                    lo8[j] = (short)f2bf(v - __uint_as_float(((unsigned)hi) << 16));
                }
            }
            xbh[it][rem] = hi8;
            xbl[it][rem] = lo8;
        }
    }
    __syncthreads();

    for (int i = 0; i < 12; i++) {
        int p = i & 1;
        bool act = (i < sd);

        // ---- MFMA: 6 independent accumulator chains (x: 9 ea, h: 12 ea) ----
        f32x4 axr = (f32x4){0.f,0.f,0.f,0.f};
        f32x4 axz = (f32x4){0.f,0.f,0.f,0.f};
        f32x4 axn = (f32x4){0.f,0.f,0.f,0.f};
        f32x4 ahr = (f32x4){0.f,0.f,0.f,0.f};
        f32x4 ahz = (f32x4){0.f,0.f,0.f,0.f};
        f32x4 ahn = (f32x4){0.f,0.f,0.f,0.f};
#pragma unroll
        for (int ks = 0; ks < 3; ks++) {
            short8 Bxh = xbh[i][ks * 64 + lane];
            short8 Bxl = xbl[i][ks * 64 + lane];
            axr = __builtin_amdgcn_mfma_f32_16x16x32_bf16(Gh[0][ks], Bxh, axr, 0, 0, 0);
            axr = __builtin_amdgcn_mfma_f32_16x16x32_bf16(Gh[0][ks], Bxl, axr, 0, 0, 0);
            axr = __builtin_amdgcn_mfma_f32_16x16x32_bf16(Gl[0][ks], Bxh, axr, 0, 0, 0);
            axz = __builtin_amdgcn_mfma_f32_16x16x32_bf16(Gh[1][ks], Bxh, axz, 0, 0, 0);
            axz = __builtin_amdgcn_mfma_f32_16x16x32_bf16(Gh[1][ks], Bxl, axz, 0, 0, 0);
            axz = __builtin_amdgcn_mfma_f32_16x16x32_bf16(Gl[1][ks], Bxh, axz, 0, 0, 0);
            axn = __builtin_amdgcn_mfma_f32_16x16x32_bf16(Gh[2][ks], Bxh, axn, 0, 0, 0);
            axn = __builtin_amdgcn_mfma_f32_16x16x32_bf16(Gh[2][ks], Bxl, axn, 0, 0, 0);
            axn = __builtin_amdgcn_mfma_f32_16x16x32_bf16(Gl[2][ks], Bxh, axn, 0, 0, 0);
        }
#pragma unroll
        for (int k32 = 0; k32 < 4; k32++) {
            short8 Bh = ((const short8*)hbh[p])[k32 * 64 + lane];
            short8 Bl = ((const short8*)hbl[p])[k32 * 64 + lane];
            ahr = __builtin_amdgcn_mfma_f32_16x16x32_bf16(Ah[0][k32], Bh, ahr, 0, 0, 0);
            ahr = __builtin_amdgcn_mfma_f32_16x16x32_bf16(Ah[0][k32], Bl, ahr, 0, 0, 0);
            ahr = __builtin_amdgcn_mfma_f32_16x16x32_bf16(Al[0][k32], Bh, ahr, 0, 0, 0);
            ahz = __builtin_amdgcn_mfma_f32_16x16x32_bf16(Ah[1][k32], Bh, ahz, 0, 0, 0);
            ahz = __builtin_amdgcn_mfma_f32_16x16x32_bf16(Ah[1][k32], Bl, ahz, 0, 0, 0);
            ahz = __builtin_amdgcn_mfma_f32_16x16x32_bf16(Al[1][k32], Bh, ahz, 0, 0, 0);
            ahn = __builtin_amdgcn_mfma_f32_16x16x32_bf16(Ah[2][k32], Bh, ahn, 0, 0, 0);
            ahn = __builtin_amdgcn_mfma_f32_16x16x32_bf16(Ah[2][k32], Bl, ahn, 0, 0, 0);
            ahn = __builtin_amdgcn_mfma_f32_16x16x32_bf16(Al[2][k32], Bh, ahn, 0, 0, 0);
        }

        // ---- lane-local GRU update ----
        if (act) {
            float hv[4]  = {h.x, h.y, h.z, h.w};
            float brv[4] = {br.x, br.y, br.z, br.w};
            float bzv[4] = {bz.x, bz.y, bz.z, bz.w};
            float bxv[4] = {bxn.x, bxn.y, bxn.z, bxn.w};
            float bhv[4] = {bhn.x, bhn.y, bhn.z, bhn.w};
#pragma unroll
            for (int cmp = 0; cmp < 4; cmp++) {
                float r = sigmoid_(axr[cmp] + ahr[cmp] + brv[cmp]);
                float z = sigmoid_(axz[cmp] + ahz[cmp] + bzv[cmp]);
                float n = tanh_(axn[cmp] + bxv[cmp] + r * (ahn[cmp] + bhv[cmp]));
                hv[cmp] = (1.f - z) * n + z * hv[cmp];
            }
            h = make_float4(hv[0], hv[1], hv[2], hv[3]);
            if (i == sd - 1) {
                float4 vout = (s < slb) ? h : make_float4(0.f, 0.f, 0.f, 0.f);
                *(float4*)&out[(b * SS + s) * (2 * DMC) + dir * DMC + j0] = vout;
            }
        }

        // ---- write h frags (split-bf16) to the other buffer ----
        {
            float hv[4] = {h.x, h.y, h.z, h.w};
            unsigned short hs_[4], ls_[4];
#pragma unroll
            for (int cmp = 0; cmp < 4; cmp++) {
                unsigned short hi = f2bf(hv[cmp]);
                float hif = __uint_as_float(((unsigned)hi) << 16);
                hs_[cmp] = hi;
                ls_[cmp] = f2bf(hv[cmp] - hif);
            }
            *(ushort4*)&hbh[1 - p][wbase] = make_ushort4(hs_[0], hs_[1], hs_[2], hs_[3]);
            *(ushort4*)&hbl[1 - p][wbase] = make_ushort4(ls_[0], ls_[1], ls_[2], ls_[3]);
        }
        __syncthreads();
    }
}

// ---------------------------------------------------------------------------
extern "C" void kernel_launch(void* const* d_in, const int* in_sizes, int n_in,
                              void* d_out, int out_size, void* d_ws, size_t ws_size,
                              hipStream_t stream) {
    const float* mel      = (const float*)d_in[0];
    const int*   durations= (const int*)  d_in[1];
    const int*   mel_len  = (const int*)  d_in[2];
    const int*   src_len  = (const int*)  d_in[3];
    const float* w1       = (const float*)d_in[4];
    const float* g1       = (const float*)d_in[5];
    const float* be1      = (const float*)d_in[6];
    const float* w2       = (const float*)d_in[7];
    const float* g2       = (const float*)d_in[8];
    const float* be2      = (const float*)d_in[9];
    const float* w_ih_f   = (const float*)d_in[10];
    const float* w_hh_f   = (const float*)d_in[11];
    const float* b_ih_f   = (const float*)d_in[12];
    const float* b_hh_f   = (const float*)d_in[13];
    const float* w_ih_b   = (const float*)d_in[14];
    const float* w_hh_b   = (const float*)d_in[15];
    const float* b_ih_b   = (const float*)d_in[16];
    const float* b_hh_b   = (const float*)d_in[17];
    float* out = (float*)d_out;

    // workspace: x | wph | wpl | wih_h | wih_l | biasc | starts
    float* x    = (float*)d_ws;
    unsigned short* wph   = (unsigned short*)(x + NROW * NM);
    unsigned short* wpl   = wph + 2 * 24 * 4 * 64 * 8;
    unsigned short* wih_h = wpl + 2 * 24 * 4 * 64 * 8;
    unsigned short* wih_l = wih_h + 48 * 3 * 64 * 8;
    float* biasc = (float*)(wih_l + 48 * 3 * 64 * 8);
    int*   starts= (int*)(biasc + 768);

    k_convprep<<<dim3(311, BB), 256, 0, stream>>>(
        mel, mel_len, w1, g1, be1, w2, g2, be2, x,
        w_hh_f, w_hh_b, w_ih_f, w_ih_b, b_ih_f, b_ih_b,
        durations, wph, wpl, wih_h, wih_l, biasc, starts);
    k_gru<<<dim3(7, 8, 2), 512, 0, stream>>>(x, wph, wpl, wih_h, wih_l, biasc,
                                             durations, starts, src_len,
                                             b_hh_f, b_hh_b, out);
}

// Round 9
// 150.421 us; speedup vs baseline: 1.0281x; 1.0281x over previous
//
#include <hip/hip_runtime.h>
#include <math.h>

// Problem constants
#define BB   8
#define SS   100
#define TT   1200        // S * DMAX
#define NM   80          // NMEL
#define DMC  128         // DM
#define KK   9
#define G3   384         // 3*DM
#define NROW (BB*TT)     // 9600

typedef __attribute__((ext_vector_type(8))) short short8;
typedef __attribute__((ext_vector_type(4))) float f32x4;
typedef __attribute__((ext_vector_type(2))) float f32x2;

__device__ __forceinline__ float sigmoid_(float v) { return 1.f / (1.f + __expf(-v)); }
__device__ __forceinline__ float tanh_(float v) {
    float a = fabsf(v);
    float e = __expf(-2.f * a);
    float t = (1.f - e) / (1.f + e);
    return copysignf(t, v);
}
__device__ __forceinline__ unsigned short f2bf(float f) {   // RNE fp32->bf16
    unsigned int u = __float_as_uint(f);
    unsigned int r = (u + 0x7fffu + ((u >> 16) & 1u)) >> 16;
    return (unsigned short)r;
}
// CDNA packed fp32 ops (VOP3P)
__device__ __forceinline__ f32x2 pk_fma(f32x2 a, f32x2 b, f32x2 c) {
    f32x2 d;
    asm("v_pk_fma_f32 %0, %1, %2, %3" : "=v"(d) : "v"(a), "v"(b), "v"(c));
    return d;
}
__device__ __forceinline__ f32x2 pk_add(f32x2 a, f32x2 b) {
    f32x2 d;
    asm("v_pk_add_f32 %0, %1, %2" : "=v"(d) : "v"(a), "v"(b));
    return d;
}
// butterfly reduce steps: xor1/xor2 via DPP quad_perm (VALU pipe, no LDS),
// xor4 via ds_swizzle. Same pairwise sums as __shfl_xor -> bit-identical.
__device__ __forceinline__ f32x2 red_x1(f32x2 c) {
    f32x2 o;
    o[0] = __int_as_float(__builtin_amdgcn_mov_dpp(__float_as_int(c[0]), 0xB1, 0xF, 0xF, true));
    o[1] = __int_as_float(__builtin_amdgcn_mov_dpp(__float_as_int(c[1]), 0xB1, 0xF, 0xF, true));
    return pk_add(c, o);
}
__device__ __forceinline__ f32x2 red_x2(f32x2 c) {
    f32x2 o;
    o[0] = __int_as_float(__builtin_amdgcn_mov_dpp(__float_as_int(c[0]), 0x4E, 0xF, 0xF, true));
    o[1] = __int_as_float(__builtin_amdgcn_mov_dpp(__float_as_int(c[1]), 0x4E, 0xF, 0xF, true));
    return pk_add(c, o);
}
__device__ __forceinline__ f32x2 red_x4(f32x2 c) {
    f32x2 o;
    o[0] = __int_as_float(__builtin_amdgcn_ds_swizzle(__float_as_int(c[0]), 0x101F));
    o[1] = __int_as_float(__builtin_amdgcn_ds_swizzle(__float_as_int(c[1]), 0x101F));
    return pk_add(c, o);
}

// ---------------------------------------------------------------------------
// Kernel CP (R20 = R17, best measured): R13 structure (600x8 conv blocks,
// 2 rows each) + DPP butterfly + hoisted weight loads. Bit-identical output.
//   prep path (bx>=600): unchanged.
// ---------------------------------------------------------------------------
__global__ __launch_bounds__(256, 4) void k_convprep(
    const float* __restrict__ mel, const int* __restrict__ mel_len,
    const float* __restrict__ w1, const float* __restrict__ g1, const float* __restrict__ be1,
    const float* __restrict__ w2, const float* __restrict__ g2, const float* __restrict__ be2,
    float* __restrict__ xout,
    const float* __restrict__ whf, const float* __restrict__ whb,
    const float* __restrict__ wif, const float* __restrict__ wib,
    const float* __restrict__ bf, const float* __restrict__ bbv,
    const int* __restrict__ dur,
    unsigned short* __restrict__ wph, unsigned short* __restrict__ wpl,
    unsigned short* __restrict__ wih_h, unsigned short* __restrict__ wih_l,
    float* __restrict__ biasc, int* __restrict__ starts) {
    int bx = blockIdx.x;
    int b  = blockIdx.y;
    int tid = threadIdx.x;

    if (bx >= 600) {
        // ---------------- prep path (88 blocks x 256 threads) ----------------
        int pid = (bx - 600) * 8 + b;            // [0, 88)
        if (pid < 87) {
            int u = pid * 256 + tid;             // [0, 22272)
            if (u < 12288) {
                int idx = u;                     // whh split-bf16
                int lane = idx & 63;
                int k32  = (idx >> 6) & 3;
                int tau  = (idx >> 8) % 24;
                int dirp = idx / (24 * 4 * 64);
                const float* w = dirp ? whb : whf;
                int gg = tau * 16 + (lane & 15);
                int kbase = k32 * 32 + (lane >> 4) * 8;
#pragma unroll
                for (int j = 0; j < 8; j++) {
                    float v = w[gg * DMC + kbase + j];
                    unsigned short hi = f2bf(v);
                    float hif = __uint_as_float(((unsigned)hi) << 16);
                    unsigned short lo = f2bf(v - hif);
                    wph[idx * 8 + j] = hi;
                    wpl[idx * 8 + j] = lo;
                }
            } else if (u < 21504) {
                int idx = u - 12288;             // wih split-bf16, [0, 9216)
                int lane = idx & 63;
                int ks   = (idx >> 6) % 3;
                int tau  = idx / (3 * 64);       // 0..47 ; dir = tau>=24
                int gate = tau * 16 + (lane & 15);
                int kb   = ks * 32 + (lane >> 4) * 8;
                const float* w = (gate < G3) ? (wif + gate * NM) : (wib + (gate - G3) * NM);
#pragma unroll
                for (int j = 0; j < 8; j++) {
                    int k = kb + j;
                    float v = (k < NM) ? w[k] : 0.f;
                    unsigned short hi = f2bf(v);
                    float hif = __uint_as_float(((unsigned)hi) << 16);
                    unsigned short lo = f2bf(v - hif);
                    wih_h[idx * 8 + j] = hi;
                    wih_l[idx * 8 + j] = lo;
                }
            } else {
                int v = u - 21504;               // biasc, [0, 768)
                biasc[v] = (v < G3) ? bf[v] : bbv[v - G3];
            }
        } else {
            // exclusive-scan of durations: 8 batches x 100, 32 lanes/batch
            int batch = tid >> 5, l = tid & 31;
            int run = 0;
#pragma unroll
            for (int c = 0; c < 4; c++) {
                int s = c * 32 + l;
                int v = (s < SS) ? dur[batch * SS + s] : 0;
                int xv = v;
#pragma unroll
                for (int off = 1; off < 32; off <<= 1) {
                    int t = __shfl_up(xv, off, 32);
                    if (l >= off) xv += t;
                }
                if (s < SS) starts[batch * SS + s] = run + xv - v;
                run += __shfl(xv, 31, 32);
            }
        }
        return;
    }

    // ------------------------- conv path --------------------------
    int t0 = bx * 2;
    int ml = mel_len[b];
    if (t0 >= ml) return;

    __shared__ __align__(16) f32x2 mp2[96];         // mp2[i] = {row0, row1}[i-8]
    __shared__ __align__(16) f32x2 part2[8][82];    // octet partials (pair rows)

    int mq = tid >> 6, g = tid & 63;
    int ms = 20 * mq;
    const float inv_sqrt = 0.9999950000374997f;     // 1/sqrt(1+1e-5)

    if (tid < 192) {
        int rr = tid / 96, i = tid - rr * 96;
        float v = 0.f;
        if (i >= 8 && i < 88) v = mel[(b * TT + t0 + rr) * NM + i - 8];
        ((float*)mp2)[i * 2 + rr] = v;
    }

    // ---- hoisted raw weight loads + BN2 scalars (latency hidden by barrier) ----
    float w1r[2][KK], w2r[2][KK], g1r[2], be1r[2];
#pragma unroll
    for (int dd = 0; dd < 2; dd++) {
        int d = g + 64 * dd;
#pragma unroll
        for (int k = 0; k < KK; k++) {
            w1r[dd][k] = w1[d * KK + k];
            w2r[dd][k] = w2[d * KK + k];
        }
        g1r[dd]  = g1[d];
        be1r[dd] = be1[d];
    }
    float g2s  = g2[0] * inv_sqrt;
    float be2s = be2[0];

    __syncthreads();

    f32x2 c[20];
#pragma unroll
    for (int m = 0; m < 20; m++) c[m] = (f32x2){0.f, 0.f};

#pragma unroll
    for (int dd = 0; dd < 2; dd++) {
        float sc = g1r[dd] * inv_sqrt;
        f32x2 w1p[KK], w2p[KK];
#pragma unroll
        for (int k = 0; k < KK; k++) {
            float a  = w1r[dd][k] * sc;
            float bq = w2r[dd][k];
            w1p[k] = (f32x2){a, a};
            w2p[k] = (f32x2){bq, bq};
        }
        float sb = be1r[dd];
        f32x2 sbp = (f32x2){sb, sb};

        f32x2 mw[12];   // sliding window (pair of rows per element)
        {
            const float4* p4 = (const float4*)(mp2 + ms);
#pragma unroll
            for (int q = 0; q < 6; q++) {
                float4 v = p4[q];
                mw[2 * q]     = (f32x2){v.x, v.y};
                mw[2 * q + 1] = (f32x2){v.z, v.w};
            }
        }
#pragma unroll
        for (int ch = 0; ch < 7; ch++) {
            // wave-uniform halo skip (bit-identical: skipped terms were
            // exact zeros in the leading accumulation slots).
            bool live = true;
            if (ch == 0) live = (mq != 0);
            if (ch == 6) live = (mq != 3);
            if (live) {
                f32x2 yv4[4];
#pragma unroll
                for (int jj = 0; jj < 4; jj++) {
                    f32x2 yv = sbp;
#pragma unroll
                    for (int k = 0; k < KK; k++) yv = pk_fma(w1p[k], mw[jj + k], yv);
                    yv[0] = fmaxf(yv[0], 0.f);
                    yv[1] = fmaxf(yv[1], 0.f);
                    yv4[jj] = yv;
                }
#pragma unroll
                for (int jj = 0; jj < 4; jj++) {
                    int off = ch * 4 + jj;
#pragma unroll
                    for (int k = 0; k < KK; k++) {
                        int mo = off - k;
                        if (mo >= 0 && mo < 20) c[mo] = pk_fma(w2p[k], yv4[jj], c[mo]);
                    }
                }
            }
            if (ch < 6) {   // slide window by 4
#pragma unroll
                for (int q = 0; q < 8; q++) mw[q] = mw[q + 4];
                const float4* p4 = (const float4*)(mp2 + ms + ch * 4 + 12);
                float4 a0 = p4[0], a1 = p4[1];
                mw[8]  = (f32x2){a0.x, a0.y};
                mw[9]  = (f32x2){a0.z, a0.w};
                mw[10] = (f32x2){a1.x, a1.y};
                mw[11] = (f32x2){a1.z, a1.w};
            }
        }
    }

    // ---- butterfly reduce over g within octets (DPP + swizzle) ----
#pragma unroll
    for (int m = 0; m < 20; m++) {
        c[m] = red_x1(c[m]);
        c[m] = red_x2(c[m]);
        c[m] = red_x4(c[m]);
    }
    if ((g & 7) == 0) {
        int p = g >> 3;
#pragma unroll
        for (int m = 0; m < 20; m++) part2[p][ms + m] = c[m];
    }
    __syncthreads();

    // ---- final: sum 8 octet partials + BN2/ReLU + store (2 rows) ----
    if (tid < 160) {
        int rr = (tid >= 80) ? 1 : 0;
        int m  = tid - 80 * rr;
        int t  = t0 + rr;
        if (t < ml) {
            float s = 0.f;
#pragma unroll
            for (int p = 0; p < 8; p++) s += part2[p][m][rr];
            float v = fmaxf(0.f, fmaf(s, g2s, be2s));
            xout[(b * TT + t) * NM + m] = v;
        }
    }
}

// ---------------------------------------------------------------------------
// Kernel C (unchanged): fused projection+GRU.
// ---------------------------------------------------------------------------
__global__ __launch_bounds__(512, 2) void k_gru(
    const float* __restrict__ x,
    const unsigned short* __restrict__ wph, const unsigned short* __restrict__ wpl,
    const unsigned short* __restrict__ wih_h, const unsigned short* __restrict__ wih_l,
    const float* __restrict__ biasc,
    const int* __restrict__ dur_all, const int* __restrict__ starts,
    const int* __restrict__ src_len,
    const float* __restrict__ bhf, const float* __restrict__ bhb,
    float* __restrict__ out) {
    int sblk = blockIdx.x;   // 0..6
    int b    = blockIdx.y;   // 0..7
    int dir  = blockIdx.z;   // 0 fwd, 1 bwd
    int s0 = sblk * 16;

    __shared__ __align__(16) short8 xbh[12][192];           // x B-frags hi, all iters
    __shared__ __align__(16) short8 xbl[12][192];           // x B-frags lo
    __shared__ __align__(16) unsigned short hbh[2][2048];   // h B-frags hi (pp)
    __shared__ __align__(16) unsigned short hbl[2][2048];   // h B-frags lo (pp)
    __shared__ int sdur[16], sstart[16];

    int tid  = threadIdx.x;
    int wave = tid >> 6, lane = tid & 63;
    int quad = lane >> 4, seg = lane & 15;

    if (tid < 16) {
        int ss = s0 + tid;
        sdur[tid]   = (ss < SS) ? dur_all[b * SS + ss] : 0;
        sstart[tid] = (ss < SS) ? starts[b * SS + ss]  : 0;
    }
    for (int i = tid; i < 2048; i += 512) { hbh[0][i] = 0; hbl[0][i] = 0; }

    // ---- w_hh A-frags (taus wave, wave+8, wave+16), persist in regs ----
    short8 Ah[3][4], Al[3][4];
    const short8* wph8 = (const short8*)wph;
    const short8* wpl8 = (const short8*)wpl;
#pragma unroll
    for (int tt = 0; tt < 3; tt++)
#pragma unroll
        for (int k32 = 0; k32 < 4; k32++) {
            int idx = ((dir * 24 + wave + 8 * tt) * 4 + k32) * 64 + lane;
            Ah[tt][k32] = wph8[idx];
            Al[tt][k32] = wpl8[idx];
        }
    // ---- w_ih A-frags (same taus, K=96), persist in regs ----
    short8 Gh[3][3], Gl[3][3];
    const short8* wih_h8 = (const short8*)wih_h;
    const short8* wih_l8 = (const short8*)wih_l;
#pragma unroll
    for (int tt = 0; tt < 3; tt++)
#pragma unroll
        for (int ks = 0; ks < 3; ks++) {
            int idx = ((dir * 24 + wave + 8 * tt) * 3 + ks) * 64 + lane;
            Gh[tt][ks] = wih_h8[idx];
            Gl[tt][ks] = wih_l8[idx];
        }

    // ---- per-lane meta & biases ----
    int s = s0 + seg;
    int sd = (s < SS) ? dur_all[b * SS + s] : 0;
    int slb = src_len[b];
    const float* bih = biasc + dir * G3;
    const float* bhh = dir ? bhb : bhf;
    int j0 = wave * 16 + quad * 4;
    float4 i_r = *(const float4*)&bih[j0];
    float4 i_z = *(const float4*)&bih[DMC + j0];
    float4 bxn = *(const float4*)&bih[2 * DMC + j0];
    float4 h_r = *(const float4*)&bhh[j0];
    float4 h_z = *(const float4*)&bhh[DMC + j0];
    float4 bhn = *(const float4*)&bhh[2 * DMC + j0];
    float4 br = make_float4(i_r.x + h_r.x, i_r.y + h_r.y, i_r.z + h_r.z, i_r.w + h_r.w);
    float4 bz = make_float4(i_z.x + h_z.x, i_z.y + h_z.y, i_z.z + h_z.z, i_z.w + h_z.w);
    float4 h = make_float4(0.f, 0.f, 0.f, 0.f);

    int idx8 = (j0 >> 5) * 64 + ((j0 >> 3) & 3) * 16 + seg;
    int wbase = idx8 * 8 + (j0 & 7);             // h-frag write addr (shorts)

    __syncthreads();   // sdur/sstart + h[0] frags visible

    // ---- stage ALL x B-frags (12 iters x 192 frag-lanes = 2304 tasks) ----
#pragma unroll
    for (int q = 0; q < 5; q++) {
        int u = tid + q * 512;
        if (u < 12 * 192) {
            int it  = u / 192;
            int rem = u - it * 192;
            int ks = rem >> 6, ln = rem & 63;
            int sg = ln & 15, qq = ln >> 4;
            int kb = ks * 32 + qq * 8;
            short8 hi8 = {0,0,0,0,0,0,0,0}, lo8 = {0,0,0,0,0,0,0,0};
            int d2 = sdur[sg];
            if (kb < NM && it < d2) {
                int t = dir ? (sstart[sg] + d2 - 1 - it) : (sstart[sg] + it);
                const float* xr = x + (size_t)(b * TT + t) * NM + kb;
#pragma unroll
                for (int j = 0; j < 8; j++) {
                    float v = xr[j];
                    unsigned short hi = f2bf(v);
                    hi8[j] = (short)hi;
                    lo8[j] = (short)f2bf(v - __uint_as_float(((unsigned)hi) << 16));
                }
            }
            xbh[it][rem] = hi8;
            xbl[it][rem] = lo8;
        }
    }
    __syncthreads();

    for (int i = 0; i < 12; i++) {
        int p = i & 1;
        bool act = (i < sd);

        // ---- MFMA: 6 independent accumulator chains (x: 9 ea, h: 12 ea) ----
        f32x4 axr = (f32x4){0.f,0.f,0.f,0.f};
        f32x4 axz = (f32x4){0.f,0.f,0.f,0.f};
        f32x4 axn = (f32x4){0.f,0.f,0.f,0.f};
        f32x4 ahr = (f32x4){0.f,0.f,0.f,0.f};
        f32x4 ahz = (f32x4){0.f,0.f,0.f,0.f};
        f32x4 ahn = (f32x4){0.f,0.f,0.f,0.f};
#pragma unroll
        for (int ks = 0; ks < 3; ks++) {
            short8 Bxh = xbh[i][ks * 64 + lane];
            short8 Bxl = xbl[i][ks * 64 + lane];
            axr = __builtin_amdgcn_mfma_f32_16x16x32_bf16(Gh[0][ks], Bxh, axr, 0, 0, 0);
            axr = __builtin_amdgcn_mfma_f32_16x16x32_bf16(Gh[0][ks], Bxl, axr, 0, 0, 0);
            axr = __builtin_amdgcn_mfma_f32_16x16x32_bf16(Gl[0][ks], Bxh, axr, 0, 0, 0);
            axz = __builtin_amdgcn_mfma_f32_16x16x32_bf16(Gh[1][ks], Bxh, axz, 0, 0, 0);
            axz = __builtin_amdgcn_mfma_f32_16x16x32_bf16(Gh[1][ks], Bxl, axz, 0, 0, 0);
            axz = __builtin_amdgcn_mfma_f32_16x16x32_bf16(Gl[1][ks], Bxh, axz, 0, 0, 0);
            axn = __builtin_amdgcn_mfma_f32_16x16x32_bf16(Gh[2][ks], Bxh, axn, 0, 0, 0);
            axn = __builtin_amdgcn_mfma_f32_16x16x32_bf16(Gh[2][ks], Bxl, axn, 0, 0, 0);
            axn = __builtin_amdgcn_mfma_f32_16x16x32_bf16(Gl[2][ks], Bxh, axn, 0, 0, 0);
        }
#pragma unroll
        for (int k32 = 0; k32 < 4; k32++) {
            short8 Bh = ((const short8*)hbh[p])[k32 * 64 + lane];
            short8 Bl = ((const short8*)hbl[p])[k32 * 64 + lane];
            ahr = __builtin_amdgcn_mfma_f32_16x16x32_bf16(Ah[0][k32], Bh, ahr, 0, 0, 0);
            ahr = __builtin_amdgcn_mfma_f32_16x16x32_bf16(Ah[0][k32], Bl, ahr, 0, 0, 0);
            ahr = __builtin_amdgcn_mfma_f32_16x16x32_bf16(Al[0][k32], Bh, ahr, 0, 0, 0);
            ahz = __builtin_amdgcn_mfma_f32_16x16x32_bf16(Ah[1][k32], Bh, ahz, 0, 0, 0);
            ahz = __builtin_amdgcn_mfma_f32_16x16x32_bf16(Ah[1][k32], Bl, ahz, 0, 0, 0);
            ahz = __builtin_amdgcn_mfma_f32_16x16x32_bf16(Al[1][k32], Bh, ahz, 0, 0, 0);
            ahn = __builtin_amdgcn_mfma_f32_16x16x32_bf16(Ah[2][k32], Bh, ahn, 0, 0, 0);
            ahn = __builtin_amdgcn_mfma_f32_16x16x32_bf16(Ah[2][k32], Bl, ahn, 0, 0, 0);
            ahn = __builtin_amdgcn_mfma_f32_16x16x32_bf16(Al[2][k32], Bh, ahn, 0, 0, 0);
        }

        // ---- lane-local GRU update ----
        if (act) {
            float hv[4]  = {h.x, h.y, h.z, h.w};
            float brv[4] = {br.x, br.y, br.z, br.w};
            float bzv[4] = {bz.x, bz.y, bz.z, bz.w};
            float bxv[4] = {bxn.x, bxn.y, bxn.z, bxn.w};
            float bhv[4] = {bhn.x, bhn.y, bhn.z, bhn.w};
#pragma unroll
            for (int cmp = 0; cmp < 4; cmp++) {
                float r = sigmoid_(axr[cmp] + ahr[cmp] + brv[cmp]);
                float z = sigmoid_(axz[cmp] + ahz[cmp] + bzv[cmp]);
                float n = tanh_(axn[cmp] + bxv[cmp] + r * (ahn[cmp] + bhv[cmp]));
                hv[cmp] = (1.f - z) * n + z * hv[cmp];
            }
            h = make_float4(hv[0], hv[1], hv[2], hv[3]);
            if (i == sd - 1) {
                float4 vout = (s < slb) ? h : make_float4(0.f, 0.f, 0.f, 0.f);
                *(float4*)&out[(b * SS + s) * (2 * DMC) + dir * DMC + j0] = vout;
            }
        }

        // ---- write h frags (split-bf16) to the other buffer ----
        {
            float hv[4] = {h.x, h.y, h.z, h.w};
            unsigned short hs_[4], ls_[4];
#pragma unroll
            for (int cmp = 0; cmp < 4; cmp++) {
                unsigned short hi = f2bf(hv[cmp]);
                float hif = __uint_as_float(((unsigned)hi) << 16);
                hs_[cmp] = hi;
                ls_[cmp] = f2bf(hv[cmp] - hif);
            }
            *(ushort4*)&hbh[1 - p][wbase] = make_ushort4(hs_[0], hs_[1], hs_[2], hs_[3]);
            *(ushort4*)&hbl[1 - p][wbase] = make_ushort4(ls_[0], ls_[1], ls_[2], ls_[3]);
        }
        __syncthreads();
    }
}

// ---------------------------------------------------------------------------
extern "C" void kernel_launch(void* const* d_in, const int* in_sizes, int n_in,
                              void* d_out, int out_size, void* d_ws, size_t ws_size,
                              hipStream_t stream) {
    const float* mel      = (const float*)d_in[0];
    const int*   durations= (const int*)  d_in[1];
    const int*   mel_len  = (const int*)  d_in[2];
    const int*   src_len  = (const int*)  d_in[3];
    const float* w1       = (const float*)d_in[4];
    const float* g1       = (const float*)d_in[5];
    const float* be1      = (const float*)d_in[6];
    const float* w2       = (const float*)d_in[7];
    const float* g2       = (const float*)d_in[8];
    const float* be2      = (const float*)d_in[9];
    const float* w_ih_f   = (const float*)d_in[10];
    const float* w_hh_f   = (const float*)d_in[11];
    const float* b_ih_f   = (const float*)d_in[12];
    const float* b_hh_f   = (const float*)d_in[13];
    const float* w_ih_b   = (const float*)d_in[14];
    const float* w_hh_b   = (const float*)d_in[15];
    const float* b_ih_b   = (const float*)d_in[16];
    const float* b_hh_b   = (const float*)d_in[17];
    float* out = (float*)d_out;

    // workspace: x | wph | wpl | wih_h | wih_l | biasc | starts
    float* x    = (float*)d_ws;
    unsigned short* wph   = (unsigned short*)(x + NROW * NM);
    unsigned short* wpl   = wph + 2 * 24 * 4 * 64 * 8;
    unsigned short* wih_h = wpl + 2 * 24 * 4 * 64 * 8;
    unsigned short* wih_l = wih_h + 48 * 3 * 64 * 8;
    float* biasc = (float*)(wih_l + 48 * 3 * 64 * 8);
    int*   starts= (int*)(biasc + 768);

    k_convprep<<<dim3(611, BB), 256, 0, stream>>>(
        mel, mel_len, w1, g1, be1, w2, g2, be2, x,
        w_hh_f, w_hh_b, w_ih_f, w_ih_b, b_ih_f, b_ih_b,
        durations, wph, wpl, wih_h, wih_l, biasc, starts);
    k_gru<<<dim3(7, 8, 2), 512, 0, stream>>>(x, wph, wpl, wih_h, wih_l, biasc,
                                             durations, starts, src_len,
                                             b_hh_f, b_hh_b, out);
}